// Round 2
// baseline (91.556 us; speedup 1.0000x reference)
//
#include <hip/hip_runtime.h>
#include <cstddef>
#include <cstdint>

// EdgeSheafLaplacian: n=1024 nodes, stalk d=8, P=32768 directed edges.
// Output Delta (8192 x 8192) f32 — dense, but only 1024 diag blocks +
// P edge blocks are nonzero (~3.3% of 8x8 blocks).
//
// R2 pipeline (single-write output):
//   memset Mmap=-1 (4MiB), diag=0 (256KiB)
//   K1 k_build:   per-edge FtF = R^T R (wave shuffles) -> atomicAdd diag[i]; Mmap[i,j]=p
//   K2 k_invsqrt: per-node D = sym(diag)+eps*I; Dis = D^{-1/2} via Newton-Schulz
//                 (valid: D = sum of Wisharts + eps*I, lambda_min >> eps, so the
//                  reference's clip(w,EPS) is inactive; eigh not needed)
//   K3 k_compact: per block u in [0,P+N): M = -sgn*R_ji^T R_ij (or diag[v]);
//                 Bval[u] = Dis_i * M * Dis_j   (coalesced 256B stores)
//   K4 k_write:   stream the whole 268MB output once, float4 stores; Mmap row
//                 in LDS selects zero vs Bval gather. No output memset at all.

namespace {
constexpr int N = 1024;     // nodes
constexpr int Dd = 8;       // stalk dim
constexpr int ND = N * Dd;  // 8192
}

__global__ void k_build(const float* __restrict__ R, const int* __restrict__ eidx,
                        int P, int* __restrict__ Mmap, float* __restrict__ diag) {
  int gid = blockIdx.x * blockDim.x + threadIdx.x;
  int u = gid >> 6;
  if (u >= P) return;
  int lane = gid & 63;
  int a = lane >> 3, b = lane & 7;
  int i = eidx[2 * u];
  int j = eidx[2 * u + 1];
  float r = R[(size_t)u * 64 + lane];
  // FtF[a][b] = sum_k R[k][a] * R[k][b]
  float acc = 0.f;
#pragma unroll
  for (int k = 0; k < 8; ++k)
    acc += __shfl(r, k * 8 + a, 64) * __shfl(r, k * 8 + b, 64);
  atomicAdd(&diag[i * 64 + lane], acc);
  if (lane == 0 && Mmap) Mmap[i * N + j] = u;
}

__global__ void k_invsqrt(const float* __restrict__ diag, float* __restrict__ Dis) {
  int gid = blockIdx.x * blockDim.x + threadIdx.x;
  int v = gid >> 6;
  if (v >= N) return;
  int lane = gid & 63;
  int a = lane >> 3, b = lane & 7;
  float dv = diag[v * 64 + lane];
  float dvt = __shfl(dv, b * 8 + a, 64);
  float A = 0.5f * (dv + dvt) + (a == b ? 1e-4f : 0.f);
  float sq = A * A;
#pragma unroll
  for (int off = 32; off; off >>= 1) sq += __shfl_xor(sq, off, 64);
  float fro = sqrtf(sq);
  float s = 1.f / fro;
  // Newton-Schulz coupled iteration: Y0 = A/fro (spectrum in (0,1]), Z0 = I.
  float Y = A * s;
  float Z = (a == b) ? 1.f : 0.f;
  for (int it = 0; it < 18; ++it) {
    float T = 0.f;
#pragma unroll
    for (int k = 0; k < 8; ++k)
      T += __shfl(Z, a * 8 + k, 64) * __shfl(Y, k * 8 + b, 64);
    float G = ((a == b) ? 1.5f : 0.f) - 0.5f * T;  // (3I - ZY)/2
    float Yn = 0.f, Zn = 0.f;
#pragma unroll
    for (int k = 0; k < 8; ++k) {
      Yn += __shfl(Y, a * 8 + k, 64) * __shfl(G, k * 8 + b, 64);
      Zn += __shfl(G, a * 8 + k, 64) * __shfl(Z, k * 8 + b, 64);
    }
    Y = Yn;
    Z = Zn;
  }
  Dis[v * 64 + lane] = Z * (1.f / sqrtf(fro));
}

// Compute normalized block u into Bval (coalesced). u < P: edge block; else diag.
__global__ void k_compact(const float* __restrict__ R, const int* __restrict__ eidx,
                          const float* __restrict__ L1, const int* __restrict__ Mmap,
                          const float* __restrict__ diag, const float* __restrict__ Dis,
                          int P, float* __restrict__ Bval) {
  int gid = blockIdx.x * blockDim.x + threadIdx.x;
  int u = gid >> 6;
  if (u >= P + N) return;
  int lane = gid & 63;
  int a = lane >> 3, b = lane & 7;
  int i, j;
  float M;
  if (u < P) {
    int p = u;
    i = eidx[2 * p];
    j = eidx[2 * p + 1];
    int rev = Mmap[j * N + i];
    float l1v = L1[i * N + j];
    float sgn = (l1v > 0.f ? 1.f : 0.f) - (l1v < 0.f ? 1.f : 0.f);
    if (rev < 0 || sgn == 0.f) {  // wave-uniform: block is exactly zero
      Bval[(size_t)u * 64 + lane] = 0.f;
      return;
    }
    float rp = R[(size_t)p * 64 + lane];
    float rr = R[(size_t)rev * 64 + lane];
    float m = 0.f;
#pragma unroll
    for (int k = 0; k < 8; ++k)
      m += __shfl(rr, k * 8 + a, 64) * __shfl(rp, k * 8 + b, 64);
    M = -sgn * m;
  } else {
    int v = u - P;
    i = v;
    j = v;
    M = diag[v * 64 + lane];
  }
  float di = Dis[i * 64 + lane];
  float dj = Dis[j * 64 + lane];
  float T = 0.f;
#pragma unroll
  for (int k = 0; k < 8; ++k)
    T += __shfl(M, a * 8 + k, 64) * __shfl(dj, k * 8 + b, 64);
  float o = 0.f;
#pragma unroll
  for (int k = 0; k < 8; ++k)
    o += __shfl(di, a * 8 + k, 64) * __shfl(T, k * 8 + b, 64);
  Bval[(size_t)u * 64 + lane] = o;
}

// One workgroup per node-row-block i: writes rows [8i, 8i+8) = 256 KB,
// fully coalesced float4 streaming; zero unless Mmap/diag says otherwise.
__global__ __launch_bounds__(256) void k_write(const int* __restrict__ Mmap,
                                               const float* __restrict__ Bval, int P,
                                               float* __restrict__ out) {
  __shared__ int mrow[N];
  int i = blockIdx.x;
  for (int t = threadIdx.x; t < N; t += 256) mrow[t] = Mmap[i * N + t];
  __syncthreads();
#pragma unroll
  for (int a = 0; a < 8; ++a) {
    float4* orow = (float4*)(out + (size_t)(i * 8 + a) * ND);
#pragma unroll
    for (int k = 0; k < 8; ++k) {
      int c4 = k * 256 + threadIdx.x;  // float4 index within the row, 0..2047
      int jb = c4 >> 1, half = c4 & 1;
      int idx = (jb == i) ? (P + i) : mrow[jb];
      float4 v = {0.f, 0.f, 0.f, 0.f};
      if (idx >= 0)
        v = *(const float4*)(Bval + (size_t)idx * 64 + a * 8 + half * 4);
      orow[c4] = v;
    }
  }
}

// Fallback scatter kernel (round-1 path) if ws_size is too small.
__global__ void k_blocks(const float* __restrict__ R, const int* __restrict__ eidx,
                         const float* __restrict__ L1, const int* __restrict__ Mmap,
                         const float* __restrict__ diag, const float* __restrict__ Dis,
                         int P, float* __restrict__ out) {
  int gid = blockIdx.x * blockDim.x + threadIdx.x;
  int u = gid >> 6;
  if (u >= P + N) return;
  int lane = gid & 63;
  int a = lane >> 3, b = lane & 7;
  int i, j;
  float M;
  if (u < P) {
    int p = u;
    i = eidx[2 * p];
    j = eidx[2 * p + 1];
    int rev;
    if (Mmap) {
      rev = Mmap[j * N + i];
    } else {
      rev = (p < P / 2) ? p + P / 2 : p - P / 2;
      if (eidx[2 * rev] != j || eidx[2 * rev + 1] != i) rev = -1;
    }
    float l1v = L1[i * N + j];
    float sgn = (l1v > 0.f ? 1.f : 0.f) - (l1v < 0.f ? 1.f : 0.f);
    if (rev < 0 || sgn == 0.f) return;
    float rp = R[(size_t)p * 64 + lane];
    float rr = R[(size_t)rev * 64 + lane];
    float m = 0.f;
#pragma unroll
    for (int k = 0; k < 8; ++k)
      m += __shfl(rr, k * 8 + a, 64) * __shfl(rp, k * 8 + b, 64);
    M = -sgn * m;
  } else {
    int v = u - P;
    i = v;
    j = v;
    M = diag[v * 64 + lane];
  }
  float di = Dis[i * 64 + lane];
  float dj = Dis[j * 64 + lane];
  float T = 0.f;
#pragma unroll
  for (int k = 0; k < 8; ++k)
    T += __shfl(M, a * 8 + k, 64) * __shfl(dj, k * 8 + b, 64);
  float o = 0.f;
#pragma unroll
  for (int k = 0; k < 8; ++k)
    o += __shfl(di, a * 8 + k, 64) * __shfl(T, k * 8 + b, 64);
  out[(size_t)(i * Dd + a) * ND + (j * Dd + b)] = o;
}

extern "C" void kernel_launch(void* const* d_in, const int* in_sizes, int n_in,
                              void* d_out, int out_size, void* d_ws, size_t ws_size,
                              hipStream_t stream) {
  const float* R = (const float*)d_in[0];
  const int* eidx = (const int*)d_in[1];
  // d_in[2] = num_edges (device scalar) — statically 1024 per setup_inputs
  const float* L1 = (const float*)d_in[3];
  float* out = (float*)d_out;
  int P = in_sizes[0] / 64;  // 32768

  size_t mmapBytes = (size_t)N * N * sizeof(int);          // 4 MiB
  size_t diagBytes = (size_t)N * 64 * sizeof(float);       // 256 KiB
  size_t bvalBytes = (size_t)(P + N) * 64 * sizeof(float); // 8.65 MB

  if (ws_size >= mmapBytes + 2 * diagBytes + bvalBytes) {
    // Fast path: single-write output.
    int* Mmap = (int*)d_ws;
    float* diag = (float*)((char*)d_ws + mmapBytes);
    float* Dis = (float*)((char*)d_ws + mmapBytes + diagBytes);
    float* Bval = (float*)((char*)d_ws + mmapBytes + 2 * diagBytes);
    hipMemsetAsync(Mmap, 0xFF, mmapBytes, stream);
    hipMemsetAsync(diag, 0, diagBytes, stream);
    long t1 = (long)P * 64;
    k_build<<<(int)((t1 + 255) / 256), 256, 0, stream>>>(R, eidx, P, Mmap, diag);
    k_invsqrt<<<(N * 64) / 256, 256, 0, stream>>>(diag, Dis);
    long t3 = (long)(P + N) * 64;
    k_compact<<<(int)((t3 + 255) / 256), 256, 0, stream>>>(R, eidx, L1, Mmap, diag,
                                                           Dis, P, Bval);
    k_write<<<N, 256, 0, stream>>>(Mmap, Bval, P, out);
    return;
  }

  // Fallback paths (round-1 structure): memset out + scatter.
  int* Mmap = nullptr;
  float* diag;
  float* Dis;
  if (ws_size >= mmapBytes + 2 * diagBytes) {
    Mmap = (int*)d_ws;
    diag = (float*)((char*)d_ws + mmapBytes);
    Dis = (float*)((char*)d_ws + mmapBytes + diagBytes);
    hipMemsetAsync(Mmap, 0xFF, mmapBytes, stream);
  } else {
    diag = (float*)d_ws;
    Dis = (float*)((char*)d_ws + diagBytes);
  }
  hipMemsetAsync(diag, 0, diagBytes, stream);
  hipMemsetAsync(out, 0, (size_t)out_size * sizeof(float), stream);
  long t1 = (long)P * 64;
  k_build<<<(int)((t1 + 255) / 256), 256, 0, stream>>>(R, eidx, P, Mmap, diag);
  k_invsqrt<<<(N * 64) / 256, 256, 0, stream>>>(diag, Dis);
  long t3 = (long)(P + N) * 64;
  k_blocks<<<(int)((t3 + 255) / 256), 256, 0, stream>>>(R, eidx, L1, Mmap, diag, Dis,
                                                        P, out);
}